// Round 9
// baseline (927.591 us; speedup 1.0000x reference)
//
#include <hip/hip_runtime.h>

#define NSHOTS 4
#define NT     512
#define NZ     256
#define NX     256
#define NRECS  128

static constexpr float DTf    = 0.001f;
static constexpr float INVDH2 = 1.0f / (10.0f * 10.0f);

#define KS     8                  // steps per phase
#define TILEZ  16                 // interior tile height (z)
#define TILEX  32                 // interior tile width  (x)
#define RPW    4                  // ext rows per wave (32 ext z / 8 waves)
#define NPR    2                  // v2f row-pairs per wave per tile
#define NWAVES 8
#define BLOCK  512
#define NWG    256                // one WG per CU; each WG owns 2 tiles
#define NPH    (NT / KS)          // 64
#define FSTR   32                 // dwords between wave flags (128 B)
#define SHOT2  (2 * NZ * NX)      // word offset tile A -> tile B (shot s+2)

typedef float v2f __attribute__((ext_vector_type(2)));
typedef unsigned long long ull;

// lane i <- lane i-1 (left x-neighbor); OOB lane 0 reads 0 (bound_ctrl=1)
__device__ __forceinline__ float nbr_left(float v) {
  return __int_as_float(__builtin_amdgcn_update_dpp(
      0, __float_as_int(v), 0x138 /*WAVE_SHR1*/, 0xf, 0xf, true));
}
// lane i <- lane i+1 (right x-neighbor); OOB lane 63 reads 0
__device__ __forceinline__ float nbr_right(float v) {
  return __int_as_float(__builtin_amdgcn_update_dpp(
      0, __float_as_int(v), 0x130 /*WAVE_SHL1*/, 0xf, 0xf, true));
}

// LLC-coherent (cross-XCD) 8B access: agent-scope relaxed -> sc0 sc1.
__device__ __forceinline__ ull pload(const ull* p) {
  return __hip_atomic_load(p, __ATOMIC_RELAXED, __HIP_MEMORY_SCOPE_AGENT);
}
__device__ __forceinline__ void pstore(ull* p, ull v) {
  __hip_atomic_store(p, v, __ATOMIC_RELAXED, __HIP_MEMORY_SCOPE_AGENT);
}

// pack (cur, prev) into one self-tagged 8B word: low 2 bits of prev's
// mantissa carry the phase tag (<= 3 ulp perturbation of halo prev only)
__device__ __forceinline__ ull pack_w(float cur, float prev, unsigned tg) {
  const unsigned hi = (__float_as_uint(prev) & ~3u) | tg;
  return ((ull)hi << 32) | (ull)__float_as_uint(cur);
}
__device__ __forceinline__ float w_cur(ull w)  { return __uint_as_float((unsigned)w); }
__device__ __forceinline__ float w_prev(ull w) {
  return __uint_as_float(((unsigned)(w >> 32)) & ~3u);
}
// per-buffer tag cycles 1,2,3 (phase q uses buffer q&1): never 0 (= memset)
__device__ __forceinline__ unsigned tag_of(int q) {
  return ((unsigned)(q >> 1) % 3u) + 1u;
}

// LDS flag ops (workgroup scope)
__device__ __forceinline__ int frel(const int* p) {
  return __hip_atomic_load(p, __ATOMIC_RELAXED, __HIP_MEMORY_SCOPE_WORKGROUP);
}
__device__ __forceinline__ void fput(int* p, int v) {
  __builtin_amdgcn_fence(__ATOMIC_RELEASE, "workgroup");
  __hip_atomic_store(p, v, __ATOMIC_RELAXED, __HIP_MEMORY_SCOPE_WORKGROUP);
}

__global__ __launch_bounds__(BLOCK, 2) void wave_pk(
    ull* __restrict__ gA, ull* __restrict__ gB,         // tagged (cur,prev) buffers
    const float* __restrict__ vp, const float* __restrict__ xwav,
    const int* __restrict__ src_z, const int* __restrict__ src_x,
    const int* __restrict__ rec_z, const int* __restrict__ rec_x,
    float* __restrict__ out)                            // [NSHOTS*NT*NRECS]
{
  const int bid  = blockIdx.x;
  const int sA   = bid >> 7;            // shots 0..1
  const int sB   = sA + 2;              // shots 2..3 (same geometry)
  const int tz   = (bid >> 3) & 15;
  const int tx   = bid & 7;
  const int tid  = threadIdx.x;
  const int w    = tid >> 6;
  const int lane = tid & 63;

  const int gz0 = tz * TILEZ - KS;      // ext origin: 32 z-rows
  const int gx0 = tx * TILEX - KS;      // 64 x-lanes (halo 8 left, 24 right)
  const int gx  = gx0 + lane;
  const int zb  = w * RPW;
  const bool xok = (unsigned)gx < (unsigned)NX;

  __shared__ float hTA[2][NWAVES][64], hBA[2][NWAVES][64];
  __shared__ float hTB[2][NWAVES][64], hBB[2][NWAVES][64];
  __shared__ int   flA[NWAVES * FSTR], flB[NWAVES * FSTR];
  __shared__ int   lzT[2][NRECS], lxT[2][NRECS];

  // init halo slots + flags + receiver tables
  hTA[0][w][lane] = 0.0f; hBA[0][w][lane] = 0.0f;
  hTA[1][w][lane] = 0.0f; hBA[1][w][lane] = 0.0f;
  hTB[0][w][lane] = 0.0f; hBB[0][w][lane] = 0.0f;
  hTB[1][w][lane] = 0.0f; hBB[1][w][lane] = 0.0f;
  if (lane == 0) {
    __hip_atomic_store(&flA[w * FSTR], 0, __ATOMIC_RELAXED, __HIP_MEMORY_SCOPE_WORKGROUP);
    __hip_atomic_store(&flB[w * FSTR], 0, __ATOMIC_RELAXED, __HIP_MEMORY_SCOPE_WORKGROUP);
  }
  if (tid < NRECS) {
    lzT[0][tid] = rec_z[sA * NRECS + tid] - tz * TILEZ;
    lxT[0][tid] = rec_x[sA * NRECS + tid] - tx * TILEX;
    lzT[1][tid] = rec_z[sB * NRECS + tid] - tz * TILEZ;
    lxT[1][tid] = rec_x[sB * NRECS + tid] - tx * TILEX;
  }

  // per-row offsets/validity; c2, d2=2-4c2 (vp shot-independent: shared A/B)
  int offRow[RPW]; unsigned okM = 0;
  v2f c22[NPR], d22[NPR], aA[NPR], bA[NPR], aB[NPR], bB[NPR];
  #pragma unroll
  for (int p = 0; p < NPR; ++p) {
    #pragma unroll
    for (int h = 0; h < 2; ++h) {
      const int i = 2 * p + h, gz = gz0 + zb + i;
      const bool ok = xok && ((unsigned)gz < (unsigned)NZ);
      if (ok) okM |= 1u << i;
      offRow[i] = ok ? ((sA * NZ + gz) * NX + gx) : 0;
      float v = ok ? vp[gz * NX + gx] : 0.0f;
      v *= DTf;
      const float c2 = v * v * INVDH2;
      if (h == 0) { c22[p].x = c2; d22[p].x = 2.0f - 4.0f * c2; }
      else        { c22[p].y = c2; d22[p].y = 2.0f - 4.0f * c2; }
    }
    aA[p] = (v2f)(0.0f); bA[p] = (v2f)(0.0f);
    aB[p] = (v2f)(0.0f); bB[p] = (v2f)(0.0f);
  }
  const bool wbT = (w >= 2 && w < 6) &&
                   ((unsigned)(lane - KS) < (unsigned)TILEX);
  const unsigned rlM = wbT ? 0u : okM;    // rows to reload/prefetch

  // source masks per tile (hasSrc wave-uniform)
  v2f smA[NPR], smB[NPR]; bool hsA, hsB;
  {
    const int slz = src_z[sA] - gz0, slx = src_x[sA] - gx0;
    const int si = slz - zb;
    hsA = ((unsigned)slx < 64u) && ((unsigned)si < (unsigned)RPW);
    const bool mine = hsA && (slx == lane);
    smA[0].x = (mine && si == 0) ? 1.f : 0.f; smA[0].y = (mine && si == 1) ? 1.f : 0.f;
    smA[1].x = (mine && si == 2) ? 1.f : 0.f; smA[1].y = (mine && si == 3) ? 1.f : 0.f;
  }
  {
    const int slz = src_z[sB] - gz0, slx = src_x[sB] - gx0;
    const int si = slz - zb;
    hsB = ((unsigned)slx < 64u) && ((unsigned)si < (unsigned)RPW);
    const bool mine = hsB && (slx == lane);
    smB[0].x = (mine && si == 0) ? 1.f : 0.f; smB[0].y = (mine && si == 1) ? 1.f : 0.f;
    smB[1].x = (mine && si == 2) ? 1.f : 0.f; smB[1].y = (mine && si == 3) ? 1.f : 0.f;
  }

  __syncthreads();   // init + tables visible; ONLY barrier in the kernel

  // receiver ownership per tile (owner is always a wbT thread)
  unsigned e0A = 0, e1A = 0, ovA[4] = {0, 0, 0, 0};
  unsigned e0B = 0, e1B = 0, ovB[4] = {0, 0, 0, 0};
  if (wbT) {
    int cA = 0, cB = 0;
    #pragma unroll 1
    for (int r = 0; r < NRECS; ++r) {
      {
        const int er = lzT[0][r], ex = lxT[0][r];
        if ((unsigned)er < (unsigned)TILEZ && (unsigned)ex < (unsigned)TILEX) {
          const int extz = er + KS;
          if ((extz >> 2) == w && ex + KS == lane) {
            const unsigned e = 0x8000u | ((unsigned)(extz & 3) << 8) | (unsigned)r;
            if (cA == 0) e0A = e; else if (cA == 1) e1A = e;
            else ovA[r >> 5] |= 1u << (r & 31);
            ++cA;
          }
        }
      }
      {
        const int er = lzT[1][r], ex = lxT[1][r];
        if ((unsigned)er < (unsigned)TILEZ && (unsigned)ex < (unsigned)TILEX) {
          const int extz = er + KS;
          if ((extz >> 2) == w && ex + KS == lane) {
            const unsigned e = 0x8000u | ((unsigned)(extz & 3) << 8) | (unsigned)r;
            if (cB == 0) e0B = e; else if (cB == 1) e1B = e;
            else ovB[r >> 5] |= 1u << (r & 31);
            ++cB;
          }
        }
      }
    }
  }
  const bool hOvA = (ovA[0] | ovA[1] | ovA[2] | ovA[3]) != 0;
  const bool hOvB = (ovB[0] | ovB[1] | ovB[2] | ovB[3]) != 0;

  auto selRow = [](const v2f (&n)[NPR], int ri) -> float {
    const v2f pp = (ri & 2) ? n[1] : n[0];
    return (ri & 1) ? pp.y : pp.x;
  };

  // one tile-step: relay spin + halo read + stencil + src + publish
  auto stepT = [&](v2f (&cur)[NPR], v2f (&nxt)[NPR], auto& hT, auto& hB,
                   int* fl, const v2f (&sm)[NPR], bool hs, float av,
                   bool pub, int u) {
    for (;;) {                           // fused relaxed spins + acquire fence
      int fm = 0x7fffffff, fp = 0x7fffffff;
      if (w > 0)          fm = frel(&fl[(w - 1) * FSTR]);
      if (w < NWAVES - 1) fp = frel(&fl[(w + 1) * FSTR]);
      if (fm >= u && fp >= u) break;
    }
    __builtin_amdgcn_fence(__ATOMIC_ACQUIRE, "workgroup");
    const int sl = u & 1;
    const float up0 = (w > 0)          ? hB[sl][w - 1][lane] : 0.0f;
    const float dn  = (w < NWAVES - 1) ? hT[sl][w + 1][lane] : 0.0f;
    #pragma unroll
    for (int p = 0; p < NPR; ++p) {
      const float cx = cur[p].x, cy = cur[p].y;
      const float upx = (p == 0)       ? up0 : cur[p - 1].y;
      const float dny = (p == NPR - 1) ? dn  : cur[p + 1].x;
      v2f ud, lr;
      ud.x = upx + cy;
      ud.y = cx + dny;
      lr.x = nbr_left(cx) + nbr_right(cx);
      lr.y = nbr_left(cy) + nbr_right(cy);
      const v2f sum = ud + lr;
      v2f t = __builtin_elementwise_fma(c22[p], sum, -nxt[p]);
      t = __builtin_elementwise_fma(d22[p], cur[p], t);
      nxt[p] = t;
    }
    if (hs) {
      const v2f av2 = { av, av };
      nxt[0] = __builtin_elementwise_fma(sm[0], av2, nxt[0]);
      nxt[1] = __builtin_elementwise_fma(sm[1], av2, nxt[1]);
    }
    if (pub) {
      hT[(u + 1) & 1][w][lane] = nxt[0].x;
      hB[(u + 1) & 1][w][lane] = nxt[1].y;
      if (lane == 0) fput(&fl[w * FSTR], u + 1);
    }
  };

  auto recst = [&](const v2f (&n)[NPR], int t, int s, unsigned e0, unsigned e1,
                   bool hOv, const unsigned (&ov)[4], const int* lz) {
    if (e0 & 0x8000u) out[(s * NT + t) * NRECS + (e0 & 127u)] = selRow(n, (e0 >> 8) & 3);
    if (e1 & 0x8000u) out[(s * NT + t) * NRECS + (e1 & 127u)] = selRow(n, (e1 >> 8) & 3);
    if (hOv) {
      #pragma unroll
      for (int wd = 0; wd < 4; ++wd) {
        unsigned m = ov[wd];
        while (m) {
          const int b = __builtin_ctz(m); m &= m - 1;
          const int r = wd * 32 + b;
          out[(s * NT + t) * NRECS + r] = selRow(n, (lz[r] + KS) & 3);
        }
      }
    }
  };

  // validate prefetched tagged words; respin stale ones; unpack into (a,b)
  auto checkRe = [&](ull (&pr)[RPW], const ull* base, unsigned tg,
                     v2f (&a2)[NPR], v2f (&b2)[NPR]) {
    unsigned need = rlM;
    #pragma unroll
    for (int i = 0; i < RPW; ++i)
      if ((need >> i) & 1)
        if ((((unsigned)(pr[i] >> 32)) & 3u) == tg) need &= ~(1u << i);
    while (need) {
      ull t[RPW];
      #pragma unroll
      for (int i = 0; i < RPW; ++i)
        if ((need >> i) & 1) t[i] = pload(base + offRow[i]);
      #pragma unroll
      for (int i = 0; i < RPW; ++i)
        if (((need >> i) & 1) && ((((unsigned)(t[i] >> 32)) & 3u) == tg)) {
          pr[i] = t[i]; need &= ~(1u << i);
        }
      if (need) __builtin_amdgcn_s_sleep(1);
    }
    #pragma unroll
    for (int i = 0; i < RPW; ++i)
      if ((rlM >> i) & 1) {
        const float cv = w_cur(pr[i]), pv = w_prev(pr[i]);
        if (i & 1) { a2[i >> 1].y = cv; b2[i >> 1].y = pv; }
        else       { a2[i >> 1].x = cv; b2[i >> 1].x = pv; }
      }
  };
  auto prefIssue = [&](ull (&pr)[RPW], const ull* base) {
    #pragma unroll
    for (int i = 0; i < RPW; ++i)
      if ((rlM >> i) & 1) pr[i] = pload(base + offRow[i]);
  };
  auto wbStore = [&](ull* base, unsigned tg, const v2f (&a2)[NPR],
                     const v2f (&b2)[NPR]) {
    if (wbT) {
      #pragma unroll
      for (int i = 0; i < RPW; ++i) {
        const float cv = (i & 1) ? a2[i >> 1].y : a2[i >> 1].x;
        const float pv = (i & 1) ? b2[i >> 1].y : b2[i >> 1].x;
        pstore(base + offRow[i], pack_w(cv, pv, tg));
      }
    }
  };

  float ampA[KS], ampB[KS];
  ull prA[RPW], prB[RPW];

  // ===== main: A leads, B lags 4 steps; per superstep {stepA; stepB} =====
  #pragma unroll 1
  for (int ph = 0; ph <= NPH; ++ph) {
    // ---- A-phase boundary (states 8ph) ----
    if (ph < NPH) {
      if (ph > 0) {
        const ull* rb = ((ph - 1) & 1) ? gB : gA;
        checkRe(prA, rb, tag_of(ph - 1), aA, bA);
      }
      hTA[0][w][lane] = aA[0].x;          // republish state 8ph (slot 0)
      hBA[0][w][lane] = aA[1].y;
      if (lane == 0) fput(&flA[w * FSTR], 8 * ph);
      if (hsA) {
        const float4 v = *(const float4*)(xwav + sA * NT + 8 * ph);
        const float4 u4 = *(const float4*)(xwav + sA * NT + 8 * ph + 4);
        ampA[0] = v.x * DTf * DTf;  ampA[1] = v.y * DTf * DTf;
        ampA[2] = v.z * DTf * DTf;  ampA[3] = v.w * DTf * DTf;
        ampA[4] = u4.x * DTf * DTf; ampA[5] = u4.y * DTf * DTf;
        ampA[6] = u4.z * DTf * DTf; ampA[7] = u4.w * DTf * DTf;
      }
    }

    #pragma unroll
    for (int tau = 0; tau < 8; ++tau) {
      const int u = 8 * ph + tau;

      // ----- A step (computes state u+1, extracts out[u]) -----
      if (ph < NPH) {
        if ((tau & 1) == 0) {
          stepT(aA, bA, hTA, hBA, flA, smA, hsA, ampA[tau], tau != 7, u);
          recst(bA, u, sA, e0A, e1A, hOvA, ovA, lzT[0]);
        } else {
          stepT(bA, aA, hTA, hBA, flA, smA, hsA, ampA[tau], tau != 7, u);
          recst(aA, u, sA, e0A, e1A, hOvA, ovA, lzT[0]);
        }
      }

      // ----- B-phase boundary at tau==4 (B states 8ph) -----
      if (tau == 4 && ph < NPH) {
        if (ph > 0) {
          const ull* rb = (((ph - 1) & 1) ? gB : gA) + SHOT2;
          checkRe(prB, rb, tag_of(ph - 1), aB, bB);
        }
        hTB[0][w][lane] = aB[0].x;
        hBB[0][w][lane] = aB[1].y;
        if (lane == 0) fput(&flB[w * FSTR], 8 * ph);
        if (hsB) {
          const float4 v = *(const float4*)(xwav + sB * NT + 8 * ph);
          const float4 u4 = *(const float4*)(xwav + sB * NT + 8 * ph + 4);
          ampB[0] = v.x * DTf * DTf;  ampB[1] = v.y * DTf * DTf;
          ampB[2] = v.z * DTf * DTf;  ampB[3] = v.w * DTf * DTf;
          ampB[4] = u4.x * DTf * DTf; ampB[5] = u4.y * DTf * DTf;
          ampB[6] = u4.z * DTf * DTf; ampB[7] = u4.w * DTf * DTf;
        }
      }

      // ----- B step (g = u-4; computes state g+1, extracts out[g]) -----
      {
        const int g = u - 4;
        if (g >= 0 && g < NT) {
          const float av = ampB[(tau + 4) & 7];
          if ((tau & 1) == 0) {
            stepT(aB, bB, hTB, hBB, flB, smB, hsB, av, (g & 7) != 7, g);
            recst(bB, g, sB, e0B, e1B, hOvB, ovB, lzT[1]);
          } else {
            stepT(bB, aB, hTB, hBB, flB, smB, hsB, av, (g & 7) != 7, g);
            recst(aB, g, sB, e0B, e1B, hOvB, ovB, lzT[1]);
          }
        }
      }

      // ----- B writeback of phase ph-1 (after B-step g=8ph-1) + prefetch -----
      if (tau == 3 && ph >= 1 && ph < NPH) {
        ull* basew = (((ph - 1) & 1) ? gB : gA) + SHOT2;
        wbStore(basew, tag_of(ph - 1), aB, bB);
        prefIssue(prB, basew);             // validated at tau==4
      }
      // ----- A writeback of phase ph (after A-step u=8ph+7) + prefetch -----
      if (tau == 7 && ph < NPH - 1) {
        ull* basew = (ph & 1) ? gB : gA;
        wbStore(basew, tag_of(ph), aA, bA);
        prefIssue(prA, basew);             // validated at next iteration top
      }
    }
  }
}

extern "C" void kernel_launch(void* const* d_in, const int* in_sizes, int n_in,
                              void* d_out, int out_size, void* d_ws, size_t ws_size,
                              hipStream_t stream) {
  const float* x     = (const float*)d_in[0];
  const float* vp    = (const float*)d_in[1];
  const int*   src_z = (const int*)d_in[2];
  const int*   src_x = (const int*)d_in[3];
  const int*   rec_z = (const int*)d_in[4];
  const int*   rec_x = (const int*)d_in[5];
  float* out = (float*)d_out;

  const size_t F = (size_t)NSHOTS * NZ * NX;
  ull* gA = (ull*)d_ws;                 // tagged (cur,prev), F words
  ull* gB = gA + F;                     // F words

  // zero both buffers: tag bits 0 never match any valid tag (1..3)
  hipMemsetAsync(gA, 0, 2 * F * sizeof(ull), stream);

  wave_pk<<<dim3(NWG), dim3(BLOCK), 0, stream>>>(
      gA, gB, vp, x, src_z, src_x, rec_z, rec_x, out);
}

// Round 10
// 471.406 us; speedup vs baseline: 1.9677x; 1.9677x over previous
//
#include <hip/hip_runtime.h>

#define NSHOTS 4
#define NT     512
#define NZ     256
#define NX     256
#define NRECS  128

static constexpr float DTf    = 0.001f;
static constexpr float INVDH2 = 1.0f / (10.0f * 10.0f);

#define KSTEPS 16                 // fused steps per phase
#define TILE   32                 // interior tile edge
#define RPT    8                  // ext rows per thread (4 float2 pairs)
#define NPAIRS 4                  // RPT/2
#define NWAVES 8
#define BLOCK  512
#define NWG    (NSHOTS * 64)      // 256 WGs, one per CU (co-resident)
#define NPHASE (NT / KSTEPS)      // 32

typedef float v2f __attribute__((ext_vector_type(2)));
typedef unsigned long long ull;

// lane i <- lane i-1 (left x-neighbor); OOB lane 0 reads 0 (bound_ctrl=1)
__device__ __forceinline__ float nbr_left(float v) {
  return __int_as_float(__builtin_amdgcn_update_dpp(
      0, __float_as_int(v), 0x138 /*WAVE_SHR1*/, 0xf, 0xf, true));
}
// lane i <- lane i+1 (right x-neighbor); OOB lane 63 reads 0
__device__ __forceinline__ float nbr_right(float v) {
  return __int_as_float(__builtin_amdgcn_update_dpp(
      0, __float_as_int(v), 0x130 /*WAVE_SHL1*/, 0xf, 0xf, true));
}

// LLC-coherent (cross-XCD) 8B access: agent-scope relaxed -> sc0 sc1.
__device__ __forceinline__ ull pload(const ull* p) {
  return __hip_atomic_load(p, __ATOMIC_RELAXED, __HIP_MEMORY_SCOPE_AGENT);
}
__device__ __forceinline__ void pstore(ull* p, ull v) {
  __hip_atomic_store(p, v, __ATOMIC_RELAXED, __HIP_MEMORY_SCOPE_AGENT);
}

// pack (cur, prev) into one self-tagged 8B word: low 2 bits of prev's
// mantissa carry the phase tag (<= 3 ulp perturbation of halo prev only)
__device__ __forceinline__ ull pack_w(float cur, float prev, unsigned tg) {
  const unsigned hi = (__float_as_uint(prev) & ~3u) | tg;
  return ((ull)hi << 32) | (ull)__float_as_uint(cur);
}
__device__ __forceinline__ float w_cur(ull w) {
  return __uint_as_float((unsigned)w);
}
__device__ __forceinline__ float w_prev(ull w) {
  return __uint_as_float(((unsigned)(w >> 32)) & ~3u);
}
// per-buffer tag cycles 1,2,3 (phase q uses buffer q&1): never 0 (= memset)
__device__ __forceinline__ unsigned tag_of(int q) {
  return ((unsigned)(q >> 1) % 3u) + 1u;
}

__global__ __launch_bounds__(BLOCK, 4) void wave_pk(
    ull* __restrict__ gA, ull* __restrict__ gB,         // tagged (cur,prev) buffers
    const float* __restrict__ vp, const float* __restrict__ xwav,
    const int* __restrict__ src_z, const int* __restrict__ src_x,
    const int* __restrict__ rec_z, const int* __restrict__ rec_x,
    float* __restrict__ out)                            // [NSHOTS*NT*NRECS]
{
  const int bid  = blockIdx.x;
  const int s    = bid >> 6;
  const int tz   = (bid >> 3) & 7;
  const int tx   = bid & 7;
  const int tid  = threadIdx.x;
  const int w    = tid >> 6;
  const int lane = tid & 63;

  const int gz0 = tz * TILE - KSTEPS;
  const int gx0 = tx * TILE - KSTEPS;
  const int gx  = gx0 + lane;
  const int zb  = w * RPT;

  __shared__ float haloTop[2][NWAVES][64];
  __shared__ float haloBot[2][NWAVES][64];
  __shared__ float recTile[2][TILE][TILE + 1];
  __shared__ int   cntS;
  __shared__ int   lzA[NRECS], lxA[NRECS];
  __shared__ unsigned pkA[NRECS];

  // ---- prologue: receiver compaction + masks (as R6) ----
  if (tid == 0) cntS = 0;
  __syncthreads();
  if (tid < NRECS) {
    const int lz = rec_z[s * NRECS + tid] - tz * TILE;
    const int lx = rec_x[s * NRECS + tid] - tx * TILE;
    lzA[tid] = lz; lxA[tid] = lx;
    if ((unsigned)lz < (unsigned)TILE && (unsigned)lx < (unsigned)TILE) {
      const int k = atomicAdd(&cntS, 1);
      pkA[k] = (unsigned)tid | ((unsigned)lz << 8) | ((unsigned)lx << 16);
    }
  }
  __syncthreads();
  const int nRec = cntS;
  int myR = 0, myLz = 0, myLx = 0;
  if (tid < nRec) {
    const unsigned p = pkA[tid];
    myR = p & 255; myLz = (p >> 8) & 31; myLx = (p >> 16) & 31;
  }
  const bool wbRow = (w >= 2 && w < 6) && (lane >= KSTEPS && lane < KSTEPS + TILE);
  const int  ilz   = (w - 2) * RPT;
  const int  ilx   = lane - KSTEPS;
  unsigned recMask = 0;
  if (wbRow) {
    for (int r = 0; r < NRECS; ++r)
      if (lxA[r] == ilx && (unsigned)(lzA[r] - ilz) < (unsigned)RPT)
        recMask |= 1u << (lzA[r] - ilz);
  }

  // source mask, packed per row-pair; hasSrcW is wave-uniform
  const int slz = src_z[s] - gz0;
  const int slx = src_x[s] - gx0;
  const bool hasSrcW = ((unsigned)slx < 64u) &&
                       ((unsigned)(slz - zb) < (unsigned)RPT);
  const bool srcMine = hasSrcW && (slx == lane);
  const int  srcI = slz - zb;
  v2f srcM2[NPAIRS];
  #pragma unroll
  for (int p = 0; p < NPAIRS; ++p) {
    srcM2[p].x = (srcMine && srcI == 2 * p)     ? 1.0f : 0.0f;
    srcM2[p].y = (srcMine && srcI == 2 * p + 1) ? 1.0f : 0.0f;
  }

  // phase-invariant per-row addresses/validity; c2 and d2=2-4c2 packed
  const bool xok = (unsigned)gx < (unsigned)NX;
  int   offRow[RPT];
  bool  okRow[RPT];
  v2f a2[NPAIRS], b2[NPAIRS], c22[NPAIRS], d22[NPAIRS];
  unsigned okMask = 0;
  #pragma unroll
  for (int p = 0; p < NPAIRS; ++p) {
    #pragma unroll
    for (int h = 0; h < 2; ++h) {
      const int i  = 2 * p + h;
      const int gz = gz0 + zb + i;
      const bool ok = xok && ((unsigned)gz < (unsigned)NZ);
      okRow[i]  = ok;
      if (ok) okMask |= 1u << i;
      offRow[i] = ok ? ((s * NZ + gz) * NX + gx) : 0;
      float v = ok ? vp[gz * NX + gx] : 0.0f;
      v *= DTf;
      const float c2 = v * v * INVDH2;
      if (h == 0) { c22[p].x = c2; d22[p].x = 2.0f - 4.0f * c2; }
      else        { c22[p].y = c2; d22[p].y = 2.0f - 4.0f * c2; }
    }
    a2[p] = (v2f)(0.0f); b2[p] = (v2f)(0.0f);
  }

  #pragma unroll 1
  for (int ph = 0; ph < NPHASE; ++ph) {
    const int t0 = ph * KSTEPS;

    // wavelet only needed by source-carrying waves (wave-uniform guard)
    float amp[KSTEPS];
    if (hasSrcW) {
      const float4* xw4 = (const float4*)(xwav + s * NT + t0);
      #pragma unroll
      for (int q = 0; q < KSTEPS / 4; ++q) {
        const float4 v = xw4[q];
        amp[4 * q + 0] = (v.x * DTf) * DTf;
        amp[4 * q + 1] = (v.y * DTf) * DTf;
        amp[4 * q + 2] = (v.z * DTf) * DTf;
        amp[4 * q + 3] = (v.w * DTf) * DTf;
      }
    }

    if (ph > 0 && !wbRow) {
      // fused poll+reload on self-tagged data words (R6-proven): tag match
      // certifies producer's phase-(ph-1) writeback AND (program order) its
      // prior reload of the buffer I overwrite this phase -> covers both
      // data-dep and anti-dep. No flags, no drains, no broadcast barrier.
      const ull* gR = (ph & 1) ? gA : gB;   // buffer[(ph-1)&1]
      const unsigned tg = tag_of(ph - 1);
      ull vw[RPT];
      unsigned need = okMask;
      while (need) {
        ull t[RPT];
        #pragma unroll
        for (int i = 0; i < RPT; ++i)
          if (need & (1u << i)) t[i] = pload(gR + offRow[i]);
        #pragma unroll
        for (int i = 0; i < RPT; ++i)
          if ((need & (1u << i)) && (((unsigned)(t[i] >> 32)) & 3u) == tg) {
            vw[i] = t[i];
            need &= ~(1u << i);
          }
        if (need) __builtin_amdgcn_s_sleep(1);
      }
      #pragma unroll
      for (int i = 0; i < RPT; ++i) {
        const float cv = okRow[i] ? w_cur(vw[i])  : 0.0f;
        const float pv = okRow[i] ? w_prev(vw[i]) : 0.0f;
        if (i & 1) { a2[i >> 1].y = cv; b2[i >> 1].y = pv; }
        else       { a2[i >> 1].x = cv; b2[i >> 1].x = pv; }
      }
    }

    // phase-start publish of state p(t0) boundary into slot 0 (step 0 reads
    // it after its barrier). Slot-0 WAR vs last phase's step-15 reads of
    // slot 1: different slots; ordering via step-0 barrier.
    haloTop[0][w][lane] = a2[0].x;
    haloBot[0][w][lane] = a2[NPAIRS - 1].y;

    float recv[KSTEPS];

    // one step, latency-hiding order:
    //   barrier -> issue halo ds_reads -> interior pairs (1,2) ->
    //   boundary pairs (0,3) -> publish nxt boundary for step tau+1 ->
    //   recTile write. ds_write drains before NEXT step's barrier; ds_read
    //   hides under interior-pair FMAs.
    auto do_step = [&](v2f (&cur)[NPAIRS], v2f (&nxt)[NPAIRS], int tau) {
      const int pb = tau & 1;            // my read slot / recTile slot
      __syncthreads();                   // slot pb published WG-wide
      const float up0 = (w > 0)          ? haloBot[pb][w - 1][lane] : 0.0f;
      const float dn7 = (w < NWAVES - 1) ? haloTop[pb][w + 1][lane] : 0.0f;
      if (tau > 0 && tid < nRec) recv[tau - 1] = recTile[1 - pb][myLz][myLx];

      auto pairC = [&](int p, float upx, float dny) {
        const float cx = cur[p].x, cy = cur[p].y;
        v2f ud, lr;
        ud.x = upx + cy;
        ud.y = cx + dny;
        lr.x = nbr_left(cx) + nbr_right(cx);
        lr.y = nbr_left(cy) + nbr_right(cy);
        const v2f sum = ud + lr;
        v2f t = __builtin_elementwise_fma(c22[p], sum, -nxt[p]);
        t = __builtin_elementwise_fma(d22[p], cur[p], t);
        nxt[p] = t;
      };
      // interior pairs first: no halo dependency -> hides halo ds_read
      pairC(1, cur[0].y, cur[2].x);
      pairC(2, cur[1].y, cur[3].x);
      // boundary pairs: consume up0/dn7 (ds_read latency now covered)
      pairC(0, up0, cur[1].x);
      pairC(3, cur[2].y, dn7);

      if (hasSrcW) {                     // wave-uniform; ~8/2048 waves pay
        const v2f av = { amp[tau], amp[tau] };
        #pragma unroll
        for (int p = 0; p < NPAIRS; ++p)
          nxt[p] = __builtin_elementwise_fma(srcM2[p], av, nxt[p]);
      }

      if (tau != KSTEPS - 1) {           // publish boundary for step tau+1
        haloTop[1 - pb][w][lane] = nxt[0].x;
        haloBot[1 - pb][w][lane] = nxt[NPAIRS - 1].y;
      }
      if (recMask) {
        #pragma unroll
        for (int i = 0; i < RPT; ++i)
          if (recMask & (1u << i))
            recTile[pb][ilz + i][ilx] = (i & 1) ? nxt[i >> 1].y : nxt[i >> 1].x;
      }
    };

    #pragma unroll
    for (int h = 0; h < KSTEPS / 2; ++h) {
      do_step(a2, b2, 2 * h);
      do_step(b2, a2, 2 * h + 1);
    }

    if (ph != NPHASE - 1 && wbRow) {
      // tagged writeback IS the inter-tile handshake (no drain, no flag)
      ull* gW = (ph & 1) ? gB : gA;      // buffer[ph&1]
      const unsigned tgw = tag_of(ph);
      #pragma unroll
      for (int p = 0; p < NPAIRS; ++p) {
        pstore(gW + offRow[2 * p],     pack_w(a2[p].x, b2[p].x, tgw));
        pstore(gW + offRow[2 * p + 1], pack_w(a2[p].y, b2[p].y, tgw));
      }
    }
    __syncthreads();                     // recTile[1] visible WG-wide

    // receiver flush (normal cached stores; read only after kernel end)
    if (tid < nRec) {
      recv[KSTEPS - 1] = recTile[1][myLz][myLx];
      #pragma unroll
      for (int t = 0; t < KSTEPS; ++t)
        out[(s * NT + (t0 + t)) * NRECS + myR] = recv[t];
    }
  }
}

extern "C" void kernel_launch(void* const* d_in, const int* in_sizes, int n_in,
                              void* d_out, int out_size, void* d_ws, size_t ws_size,
                              hipStream_t stream) {
  const float* x     = (const float*)d_in[0];
  const float* vp    = (const float*)d_in[1];
  const int*   src_z = (const int*)d_in[2];
  const int*   src_x = (const int*)d_in[3];
  const int*   rec_z = (const int*)d_in[4];
  const int*   rec_x = (const int*)d_in[5];
  float* out = (float*)d_out;

  const size_t F = (size_t)NSHOTS * NZ * NX;
  ull* gA = (ull*)d_ws;                 // tagged (cur,prev), F words
  ull* gB = gA + F;                     // F words

  // zero both buffers: tag bits 0 never match any valid tag (1..3)
  hipMemsetAsync(gA, 0, 2 * F * sizeof(ull), stream);

  wave_pk<<<dim3(NWG), dim3(BLOCK), 0, stream>>>(
      gA, gB, vp, x, src_z, src_x, rec_z, rec_x, out);
}